// Round 1
// baseline (2377.334 us; speedup 1.0000x reference)
//
#include <hip/hip_runtime.h>
#include <cstddef>

#define B   128
#define TS  1024
#define E   1024
#define H   1024
#define DA  1024
#define DE  1024
#define V   50257
#define EV  50657
#define NPAD (EV - V)   // 400

__device__ __forceinline__ float sigmoidf_(float x) { return 1.f / (1.f + expf(-x)); }

// ---------------------------------------------------------------------------
// Build lstm_in = [emb_table[tok] | prev_out]  (B x 2E)
// ---------------------------------------------------------------------------
__global__ __launch_bounds__(256) void build_lstm_in_kernel(
    const int* __restrict__ tok, const float* __restrict__ prev_out,
    const float* __restrict__ emb_table, float* __restrict__ lstm_in)
{
    int idx = blockIdx.x * 256 + threadIdx.x;   // < B*2E = 262144
    int b = idx >> 11;
    int j = idx & 2047;
    float v;
    if (j < E) v = emb_table[(size_t)tok[b] * E + j];
    else       v = prev_out[(size_t)b * E + (j - E)];
    lstm_in[idx] = v;
}

// ---------------------------------------------------------------------------
// out[b][n] = sum_k X[b][k] * Wrow(n)[k] (+ bias1[n] + bias2[n])
// X = [X1 (BxK1) | X2 (BxK2)], Wrow(n)[k] = k<K1 ? W1[n*ldw1+k] : W2[n*ldw2+k-K1]
// Tile: BM=128 (all batch), BN=32, BK=32. 256 threads, 16 outputs each.
// ---------------------------------------------------------------------------
__global__ __launch_bounds__(256) void gemm_xwt_kernel(
    const float* __restrict__ X1, int K1,
    const float* __restrict__ X2, int K2,
    const float* __restrict__ W1, int ldw1,
    const float* __restrict__ W2, int ldw2,
    const float* __restrict__ bias1, const float* __restrict__ bias2,
    float* __restrict__ out, int N)
{
    __shared__ float Xs[32][129];  // [k][b]
    __shared__ float Ws[32][33];   // [n][k]
    const int tid = threadIdx.x;
    const int n0  = blockIdx.x * 32;
    const int K   = K1 + K2;
    const int tn  = tid & 15;          // n = n0 + tn + 16*i
    const int tb  = (tid >> 4) * 8;    // 8 consecutive batch rows
    float acc[2][8];
#pragma unroll
    for (int i = 0; i < 2; i++)
#pragma unroll
        for (int j = 0; j < 8; j++) acc[i][j] = 0.f;

    for (int k0 = 0; k0 < K; k0 += 32) {
#pragma unroll
        for (int i = 0; i < 16; i++) {
            int idx = tid + i * 256;       // 0..4095
            int bb  = idx >> 5;            // 0..127
            int kk  = idx & 31;
            int k   = k0 + kk;
            Xs[kk][bb] = (k < K1) ? X1[(size_t)bb * K1 + k]
                                  : X2[(size_t)bb * K2 + (k - K1)];
        }
#pragma unroll
        for (int i = 0; i < 4; i++) {
            int idx = tid + i * 256;       // 0..1023
            int nn  = idx >> 5;            // 0..31
            int kk  = idx & 31;
            int n   = n0 + nn;
            int k   = k0 + kk;
            float v = 0.f;
            if (n < N) v = (k < K1) ? W1[(size_t)n * ldw1 + k]
                                    : W2[(size_t)n * ldw2 + (k - K1)];
            Ws[nn][kk] = v;
        }
        __syncthreads();
#pragma unroll
        for (int kk = 0; kk < 32; kk++) {
            float w0 = Ws[tn][kk];
            float w1 = Ws[tn + 16][kk];
#pragma unroll
            for (int j = 0; j < 8; j++) {
                float x = Xs[kk][tb + j];
                acc[0][j] += w0 * x;
                acc[1][j] += w1 * x;
            }
        }
        __syncthreads();
    }
#pragma unroll
    for (int i = 0; i < 2; i++) {
        int n = n0 + tn + i * 16;
        if (n >= N) continue;
        float bias = 0.f;
        if (bias1) bias += bias1[n];
        if (bias2) bias += bias2[n];
#pragma unroll
        for (int j = 0; j < 8; j++)
            out[(size_t)(tb + j) * N + n] = acc[i][j] + bias;
    }
}

// ---------------------------------------------------------------------------
// out[b][n] = sum_k X[b][k] * W[k*N + n]   (query = h @ attn_w)
// ---------------------------------------------------------------------------
__global__ __launch_bounds__(256) void gemm_xw_kernel(
    const float* __restrict__ X, int K,
    const float* __restrict__ W, int N,
    float* __restrict__ out)
{
    __shared__ float Xs[32][129];
    __shared__ float Ws[32][33];   // [k][n]
    const int tid = threadIdx.x;
    const int n0  = blockIdx.x * 32;
    const int tn  = tid & 15;
    const int tb  = (tid >> 4) * 8;
    float acc[2][8];
#pragma unroll
    for (int i = 0; i < 2; i++)
#pragma unroll
        for (int j = 0; j < 8; j++) acc[i][j] = 0.f;

    for (int k0 = 0; k0 < K; k0 += 32) {
#pragma unroll
        for (int i = 0; i < 16; i++) {
            int idx = tid + i * 256;
            int bb  = idx >> 5;
            int kk  = idx & 31;
            Xs[kk][bb] = X[(size_t)bb * K + k0 + kk];
        }
#pragma unroll
        for (int i = 0; i < 4; i++) {
            int idx = tid + i * 256;
            int kk  = idx >> 5;
            int nn  = idx & 31;
            Ws[kk][nn] = W[(size_t)(k0 + kk) * N + n0 + nn];
        }
        __syncthreads();
#pragma unroll
        for (int kk = 0; kk < 32; kk++) {
            float w0 = Ws[kk][tn];
            float w1 = Ws[kk][tn + 16];
#pragma unroll
            for (int j = 0; j < 8; j++) {
                float x = Xs[kk][tb + j];
                acc[0][j] += w0 * x;
                acc[1][j] += w1 * x;
            }
        }
        __syncthreads();
    }
#pragma unroll
    for (int i = 0; i < 2; i++) {
        int n = n0 + tn + i * 16;
#pragma unroll
        for (int j = 0; j < 8; j++)
            out[(size_t)(tb + j) * N + n] = acc[i][j];
    }
}

// ---------------------------------------------------------------------------
// LSTM cell elementwise
// ---------------------------------------------------------------------------
__global__ __launch_bounds__(256) void lstm_cell_kernel(
    const float* __restrict__ gates, const float* __restrict__ c0,
    float* __restrict__ h_out, float* __restrict__ c_out)
{
    int idx = blockIdx.x * 256 + threadIdx.x;  // < B*H
    int b = idx >> 10, j = idx & 1023;
    const float* g = gates + (size_t)b * 4096;
    float i_ = sigmoidf_(g[j]);
    float f_ = sigmoidf_(g[j + 1024]);
    float g_ = tanhf(g[j + 2048]);
    float o_ = sigmoidf_(g[j + 3072]);
    float c = f_ * c0[idx] + i_ * g_;
    float h = o_ * tanhf(c);
    h_out[idx] = h;
    c_out[idx] = c;
}

// ---------------------------------------------------------------------------
// att[b][t] = mask ? dot(query[b], enc_proj[b][t]) : -1e18
// block = 256 (4 waves), each block does 16 t's for one b. Masked t skipped.
// ---------------------------------------------------------------------------
__global__ __launch_bounds__(256) void attn_logits_kernel(
    const float* __restrict__ query, const float* __restrict__ enc_proj,
    const int* __restrict__ mask, float* __restrict__ att)
{
    __shared__ float4 qs[256];
    int b     = blockIdx.x >> 6;
    int chunk = blockIdx.x & 63;
    int tid   = threadIdx.x;
    qs[tid] = ((const float4*)(query + (size_t)b * DA))[tid];
    __syncthreads();
    int wave = tid >> 6, lane = tid & 63;
#pragma unroll
    for (int tt = 0; tt < 4; tt++) {
        int t = chunk * 16 + wave * 4 + tt;
        if (mask[(size_t)b * TS + t] == 0) {
            if (lane == 0) att[(size_t)b * TS + t] = -1e18f;
            continue;
        }
        const float4* ep = (const float4*)(enc_proj + ((size_t)b * TS + t) * DA);
        float sum = 0.f;
#pragma unroll
        for (int i = 0; i < 4; i++) {
            float4 v = ep[lane + i * 64];
            float4 q = qs[lane + i * 64];
            sum += v.x * q.x + v.y * q.y + v.z * q.z + v.w * q.w;
        }
#pragma unroll
        for (int off = 32; off; off >>= 1) sum += __shfl_down(sum, off);
        if (lane == 0) att[(size_t)b * TS + t] = sum;
    }
}

// ---------------------------------------------------------------------------
// score = softmax(att) per row (TS=1024), one block per b
// ---------------------------------------------------------------------------
__global__ __launch_bounds__(256) void softmax_score_kernel(
    const float* __restrict__ att, float* __restrict__ score)
{
    __shared__ float red[8];
    int b = blockIdx.x, tid = threadIdx.x;
    float4 v = ((const float4*)(att + (size_t)b * TS))[tid];
    float m = fmaxf(fmaxf(v.x, v.y), fmaxf(v.z, v.w));
#pragma unroll
    for (int off = 32; off; off >>= 1) m = fmaxf(m, __shfl_down(m, off));
    int wave = tid >> 6, lane = tid & 63;
    if (lane == 0) red[wave] = m;
    __syncthreads();
    float M = fmaxf(fmaxf(red[0], red[1]), fmaxf(red[2], red[3]));
    float e0 = expf(v.x - M), e1 = expf(v.y - M), e2 = expf(v.z - M), e3 = expf(v.w - M);
    float s = e0 + e1 + e2 + e3;
#pragma unroll
    for (int off = 32; off; off >>= 1) s += __shfl_down(s, off);
    __syncthreads();
    if (lane == 0) red[wave] = s;
    __syncthreads();
    float inv = 1.f / (red[0] + red[1] + red[2] + red[3]);
    float4 o = {e0 * inv, e1 * inv, e2 * inv, e3 * inv};
    ((float4*)(score + (size_t)b * TS))[tid] = o;
}

// ---------------------------------------------------------------------------
// ctx partial: partial[s][b][d] = sum_{t in slice s} score[b][t]*enc_mem[b][t][d]
// 8 slices of 128 t. Skips t with score==0 (masked -> exact 0).
// ---------------------------------------------------------------------------
__global__ __launch_bounds__(256) void ctx_partial_kernel(
    const float* __restrict__ score, const float* __restrict__ enc_mem,
    float* __restrict__ partial)
{
    int b = blockIdx.x >> 3;
    int s = blockIdx.x & 7;
    int tid = threadIdx.x;
    __shared__ float ss[128];
    if (tid < 128) ss[tid] = score[(size_t)b * TS + s * 128 + tid];
    __syncthreads();
    const float4* em = (const float4*)(enc_mem + ((size_t)b * TS + s * 128) * DE);
    float4 acc = {0.f, 0.f, 0.f, 0.f};
    for (int t = 0; t < 128; t++) {
        float sc = ss[t];
        if (sc == 0.f) continue;   // masked token: exact zero, skip the 4KB read
        float4 v = em[(size_t)t * 256 + tid];
        acc.x += sc * v.x; acc.y += sc * v.y; acc.z += sc * v.z; acc.w += sc * v.w;
    }
    ((float4*)(partial + ((size_t)(s * B + b)) * DE))[tid] = acc;
}

__global__ __launch_bounds__(256) void ctx_reduce_kernel(
    const float* __restrict__ partial, float* __restrict__ ctx)
{
    int idx = blockIdx.x * 256 + threadIdx.x;  // < B*DE
    float s = 0.f;
#pragma unroll
    for (int p = 0; p < 8; p++) s += partial[(size_t)p * (B * DE) + idx];
    ctx[idx] = s;
}

// ---------------------------------------------------------------------------
// copy_gate[b] = sigmoid(ctx.wc + h.ws + emb.wi + b)
// ---------------------------------------------------------------------------
__global__ __launch_bounds__(64) void copy_gate_kernel(
    const float* __restrict__ ctx, const float* __restrict__ h,
    const float* __restrict__ emb /* lstm_in, row stride 2048 */,
    const float* __restrict__ wc, const float* __restrict__ wsv,
    const float* __restrict__ wi, const float* __restrict__ bb,
    float* __restrict__ cg)
{
    int b = blockIdx.x, lane = threadIdx.x;
    float s = 0.f;
    for (int i = lane; i < 1024; i += 64)
        s += ctx[(size_t)b * 1024 + i] * wc[i]
           + h[(size_t)b * 1024 + i] * wsv[i]
           + emb[(size_t)b * 2048 + i] * wi[i];
#pragma unroll
    for (int off = 32; off; off >>= 1) s += __shfl_down(s, off);
    if (lane == 0) cg[b] = 1.f / (1.f + expf(-(s + bb[0])));
}

// ---------------------------------------------------------------------------
// per-row max & sum-exp over [vocab_logits | 400 x 1e-6]
// ---------------------------------------------------------------------------
__global__ __launch_bounds__(256) void row_reduce_kernel(
    const float* __restrict__ vl, float* __restrict__ rmax, float* __restrict__ rsum)
{
    __shared__ float red[8];
    int b = blockIdx.x, tid = threadIdx.x;
    float m = -1e30f;
    for (int v = tid; v < V; v += 256) m = fmaxf(m, vl[(size_t)b * V + v]);
    m = fmaxf(m, 1e-6f);
#pragma unroll
    for (int off = 32; off; off >>= 1) m = fmaxf(m, __shfl_down(m, off));
    int wave = tid >> 6, lane = tid & 63;
    if (lane == 0) red[wave] = m;
    __syncthreads();
    float M = fmaxf(fmaxf(red[0], red[1]), fmaxf(red[2], red[3]));
    float s = 0.f;
    for (int v = tid; v < V; v += 256) s += expf(vl[(size_t)b * V + v] - M);
#pragma unroll
    for (int off = 32; off; off >>= 1) s += __shfl_down(s, off);
    __syncthreads();
    if (lane == 0) red[wave] = s;
    __syncthreads();
    if (tid == 0) {
        rmax[b] = M;
        rsum[b] = red[0] + red[1] + red[2] + red[3] + (float)NPAD * expf(1e-6f - M);
    }
}

// ---------------------------------------------------------------------------
// out[b][v] = (1-cg[b]) * exp(logit - M)/S    (pre-scatter, pre-log)
// ---------------------------------------------------------------------------
__global__ __launch_bounds__(256) void final_write_kernel(
    const float* __restrict__ vl, const float* __restrict__ rmax,
    const float* __restrict__ rsum, const float* __restrict__ cg,
    float* __restrict__ out)
{
    int b = blockIdx.y;
    int v = blockIdx.x * 256 + threadIdx.x;
    if (v >= EV) return;
    float logit = (v < V) ? vl[(size_t)b * V + v] : 1e-6f;
    float gen = expf(logit - rmax[b]) / rsum[b];
    out[(size_t)b * EV + v] = (1.f - cg[b]) * gen;
}

__global__ __launch_bounds__(256) void scatter_kernel(
    const int* __restrict__ extend_art, const float* __restrict__ score,
    const float* __restrict__ cg, float* __restrict__ out)
{
    int b = blockIdx.x, tid = threadIdx.x;
    float g = cg[b];
    for (int t = tid; t < TS; t += 256) {
        float val = score[(size_t)b * TS + t] * g;
        int dst = extend_art[(size_t)b * TS + t];
        atomicAdd(&out[(size_t)b * EV + dst], val);
    }
}

__global__ __launch_bounds__(256) void log_kernel(float* __restrict__ out)
{
    size_t idx = (size_t)blockIdx.x * 256 + threadIdx.x;
    if (idx < (size_t)B * EV) out[idx] = logf(out[idx] + 1e-8f);
}

// ---------------------------------------------------------------------------
extern "C" void kernel_launch(void* const* d_in, const int* in_sizes, int n_in,
                              void* d_out, int out_size, void* d_ws, size_t ws_size,
                              hipStream_t stream)
{
    const int*   tok        = (const int*)d_in[0];
    const float* prev_out   = (const float*)d_in[1];
    const float* h0         = (const float*)d_in[2];
    const float* c0         = (const float*)d_in[3];
    const float* enc_mem    = (const float*)d_in[4];
    const float* enc_proj   = (const float*)d_in[5];
    const int*   mask       = (const int*)d_in[6];
    const int*   extend_art = (const int*)d_in[7];
    const float* emb_table  = (const float*)d_in[8];
    const float* W_ih       = (const float*)d_in[9];
    const float* W_hh       = (const float*)d_in[10];
    const float* b_ih       = (const float*)d_in[11];
    const float* b_hh       = (const float*)d_in[12];
    const float* attn_w     = (const float*)d_in[13];
    const float* proj_W     = (const float*)d_in[14];
    const float* proj_b     = (const float*)d_in[15];
    const float* copy_wc    = (const float*)d_in[16];
    const float* copy_ws_   = (const float*)d_in[17];
    const float* copy_wi    = (const float*)d_in[18];
    const float* copy_b     = (const float*)d_in[19];

    float* out = (float*)d_out;
    float* ws  = (float*)d_ws;

    // workspace layout (floats)
    float* lstm_in = ws;                 // 262144
    float* gates   = ws + 262144;        // 524288
    float* query   = ws + 786432;        // 131072
    float* att     = ws + 917504;        // 131072
    float* part    = ws + 1048576;       // 8*131072
    float* ctx     = ws + 2097152;       // 131072
    float* cg      = ws + 2228224;       // 128
    float* rmax    = ws + 2228352;       // 128
    float* rsum    = ws + 2228480;       // 128
    float* vl      = ws + 2228608;       // 6432896

    float* out_log   = out;              // 128*50657
    float* out_h     = out + 6484096;    // 131072
    float* out_c     = out + 6615168;    // 131072
    float* out_dec   = out + 6746240;    // 131072
    float* out_score = out + 6877312;    // 131072

    build_lstm_in_kernel<<<1024, 256, 0, stream>>>(tok, prev_out, emb_table, lstm_in);
    gemm_xwt_kernel<<<128, 256, 0, stream>>>(lstm_in, 2 * E, h0, H,
                                             W_ih, 2 * E, W_hh, H,
                                             b_ih, b_hh, gates, 4 * H);
    lstm_cell_kernel<<<512, 256, 0, stream>>>(gates, c0, out_h, out_c);
    gemm_xw_kernel<<<32, 256, 0, stream>>>(out_h, H, attn_w, DA, query);
    attn_logits_kernel<<<B * 64, 256, 0, stream>>>(query, enc_proj, mask, att);
    softmax_score_kernel<<<B, 256, 0, stream>>>(att, out_score);
    ctx_partial_kernel<<<B * 8, 256, 0, stream>>>(out_score, enc_mem, part);
    ctx_reduce_kernel<<<512, 256, 0, stream>>>(part, ctx);
    gemm_xwt_kernel<<<32, 256, 0, stream>>>(out_h, H, ctx, DE,
                                            proj_W, H + DE, proj_W + H, H + DE,
                                            proj_b, nullptr, out_dec, E);
    copy_gate_kernel<<<B, 64, 0, stream>>>(ctx, out_h, lstm_in,
                                           copy_wc, copy_ws_, copy_wi, copy_b, cg);
    gemm_xwt_kernel<<<(V + 31) / 32, 256, 0, stream>>>(out_dec, E, nullptr, 0,
                                                       emb_table, E, nullptr, 0,
                                                       nullptr, nullptr, vl, V);
    row_reduce_kernel<<<B, 256, 0, stream>>>(vl, rmax, rsum);
    dim3 fw_grid((EV + 255) / 256, B);
    final_write_kernel<<<fw_grid, 256, 0, stream>>>(vl, rmax, rsum, cg, out_log);
    scatter_kernel<<<B, 256, 0, stream>>>(extend_art, out_score, cg, out_log);
    log_kernel<<<(B * EV + 255) / 256, 256, 0, stream>>>(out_log);
}